// Round 8
// baseline (157.876 us; speedup 1.0000x reference)
//
#include <hip/hip_runtime.h>
#include <math.h>
#include <stdint.h>

#define B_ 4
#define S_ 1024
#define F_ 512    // W*DIM = HEADS*HD
#define HD 128
#define SOFT_C 4.0f   // fixed exp-centering; |S| << 88 so no running max needed

typedef __attribute__((ext_vector_type(8))) short short8;
typedef __attribute__((ext_vector_type(4))) float f32x4;
typedef __attribute__((ext_vector_type(4))) unsigned int u32x4;
typedef __attribute__((ext_vector_type(2))) unsigned int u32x2;

__device__ __forceinline__ unsigned short f2bf(float f) {
    unsigned int u = __float_as_uint(f);
    u = (u + 0x7FFFu + ((u >> 16) & 1u)) >> 16;
    return (unsigned short)u;
}
__device__ __forceinline__ float bf2f(unsigned int s) {
    return __uint_as_float(s << 16);
}
__device__ __forceinline__ void pack_hilo(const float* v, u32x4& hi, u32x4& lo) {
    #pragma unroll
    for (int p = 0; p < 4; ++p) {
        unsigned int h0 = f2bf(v[2 * p]), h1 = f2bf(v[2 * p + 1]);
        float l0 = v[2 * p] - bf2f(h0), l1 = v[2 * p + 1] - bf2f(h1);
        hi[p] = h0 | (h1 << 16);
        lo[p] = (unsigned int)f2bf(l0) | ((unsigned int)f2bf(l1) << 16);
    }
}

// ---------------------------------------------------------------------------
// K1 k_qkv (fused prep): blk<512 project QKV via MFMA with INLINE emb hi/lo
// packing and per-block strength vector (block 0 exports sv_g).
// Q/K operand-swapped (lane = channel, contiguous stores); V lane = row into
// tile-blocked yvt2.  blk>=512: xbar blocks with INLINE pos-MLP softmax.
//   yqh/ykh[bh][s][d=128] ; yvt2[bh][s/64][d][s%64]
// ---------------------------------------------------------------------------
__global__ __launch_bounds__(256) void k_qkv(
    const float* __restrict__ x, const float* __restrict__ strength,
    const int* __restrict__ embed_id,
    const float* __restrict__ qw, const float* __restrict__ kw,
    const float* __restrict__ vw,
    const float* __restrict__ str_w, const float* __restrict__ str_b,
    const float* __restrict__ pos,
    const float* __restrict__ pw1, const float* __restrict__ pb1,
    const float* __restrict__ pw2, const float* __restrict__ pb2,
    const float* __restrict__ head_w,
    unsigned short* __restrict__ yqh, unsigned short* __restrict__ ykh,
    unsigned short* __restrict__ yvt2,
    float* __restrict__ xbar, float* __restrict__ sv_g)
{
    __shared__ float p_s[4096];          // pos-softmax (xbar blocks) 16KB
    __shared__ float part_s[4][64];
    __shared__ float sv_s[64], svq_s[64];
    __shared__ float red_s[4][4];
    __shared__ float inv_s[4];
    __shared__ float xr_s[4][8];

    const int tid  = threadIdx.x;
    const int wv   = tid >> 6;
    const int lane = tid & 63;
    const int quad = lane >> 4;
    const int l15  = lane & 15;
    const float SCALE = 0.08838834764831845f;  // 1/sqrt(128)

    if (blockIdx.x >= 512) {
        // ================= xbar blocks: inline pos-MLP + softmax ===========
        const int bi = blockIdx.x - 512;
        const int b = bi >> 6, c = bi & 63;
        float w1_[9], b1_[3], w2_[24], b2_[8], hw_[32];
        #pragma unroll
        for (int i = 0; i < 9; ++i)  w1_[i] = pw1[i];
        #pragma unroll
        for (int i = 0; i < 3; ++i)  b1_[i] = pb1[i];
        #pragma unroll
        for (int i = 0; i < 24; ++i) w2_[i] = pw2[i];
        #pragma unroll
        for (int i = 0; i < 8; ++i)  b2_[i] = pb2[i];
        #pragma unroll
        for (int i = 0; i < 32; ++i) hw_[i] = head_w[i];

        float ps[4] = {0.f, 0.f, 0.f, 0.f};
        #pragma unroll
        for (int k = 0; k < 4; ++k) {
            const int t = k * 256 + tid;
            float p0 = pos[(b * S_ + t) * 3 + 0];
            float p1 = pos[(b * S_ + t) * 3 + 1];
            float p2 = pos[(b * S_ + t) * 3 + 2];
            float h0 = fmaxf(0.f, p0 * w1_[0] + p1 * w1_[1] + p2 * w1_[2] + b1_[0]);
            float h1 = fmaxf(0.f, p0 * w1_[3] + p1 * w1_[4] + p2 * w1_[5] + b1_[1]);
            float h2 = fmaxf(0.f, p0 * w1_[6] + p1 * w1_[7] + p2 * w1_[8] + b1_[2]);
            float ph[8];
            #pragma unroll
            for (int o8 = 0; o8 < 8; ++o8)
                ph[o8] = h0 * w2_[o8 * 3] + h1 * w2_[o8 * 3 + 1] + h2 * w2_[o8 * 3 + 2] + b2_[o8];
            #pragma unroll
            for (int h = 0; h < 4; ++h) {
                float A = 0.f;
                #pragma unroll
                for (int o8 = 0; o8 < 8; ++o8) A += ph[o8] * hw_[h * 8 + o8];
                float e = __expf(-A - 1.0f);
                p_s[h * 1024 + t] = e;
                ps[h] += e;
            }
        }
        #pragma unroll
        for (int h = 0; h < 4; ++h)
            #pragma unroll
            for (int off = 1; off < 64; off <<= 1)
                ps[h] += __shfl_xor(ps[h], off);
        if (lane == 0)
            #pragma unroll
            for (int h = 0; h < 4; ++h) red_s[wv][h] = ps[h];
        __syncthreads();
        if (tid < 4)
            inv_s[tid] = 1.f / (red_s[0][tid] + red_s[1][tid] + red_s[2][tid] + red_s[3][tid]);
        __syncthreads();

        const float* xc = x + (size_t)b * 524288 + c * 8192;
        float acc[8] = {};
        #pragma unroll
        for (int rr = 0; rr < 4; ++rr) {
            const int s = tid * 4 + rr;
            f32x4 x0 = *(const f32x4*)(xc + s * 8);
            f32x4 x1 = *(const f32x4*)(xc + s * 8 + 4);
            float p0 = p_s[s], p1 = p_s[1024 + s], p2 = p_s[2048 + s], p3 = p_s[3072 + s];
            acc[0] += p0 * x0[0]; acc[1] += p0 * x0[1];
            acc[2] += p1 * x0[2]; acc[3] += p1 * x0[3];
            acc[4] += p2 * x1[0]; acc[5] += p2 * x1[1];
            acc[6] += p3 * x1[2]; acc[7] += p3 * x1[3];
        }
        #pragma unroll
        for (int j = 0; j < 8; ++j)
            #pragma unroll
            for (int off = 1; off < 64; off <<= 1)
                acc[j] += __shfl_xor(acc[j], off);
        if (lane == 0)
            #pragma unroll
            for (int j = 0; j < 8; ++j) xr_s[wv][j] = acc[j];
        __syncthreads();
        if (tid < 8)
            xbar[(b * 8 + tid) * 64 + c] = (xr_s[0][tid] + xr_s[1][tid]
                + xr_s[2][tid] + xr_s[3][tid]) * inv_s[tid >> 1];
        return;
    }

    // ================= projection blocks ===================================
    // strength vector (per block; block 0 exports to sv_g)
    {
        const float* wrow = str_w + lane * 512 + wv * 128;
        const float* st   = strength + wv * 128;
        float acc = 0.f;
        #pragma unroll
        for (int j4 = 0; j4 < 32; ++j4) {
            f32x4 wv4 = *(const f32x4*)(wrow + j4 * 4);
            f32x4 s4  = *(const f32x4*)(st + j4 * 4);
            acc += wv4[0] * s4[0] + wv4[1] * s4[1] + wv4[2] * s4[2] + wv4[3] * s4[3];
        }
        part_s[wv][lane] = acc;
    }
    __syncthreads();
    if (wv == 0) {
        float v = part_s[0][lane] + part_s[1][lane] + part_s[2][lane]
                + part_s[3][lane] + str_b[lane];
        sv_s[lane] = v;
        svq_s[lane] = v * SCALE;
    }
    __syncthreads();
    if (blockIdx.x == 0 && tid < 64) sv_g[tid] = sv_s[tid];

    const int r0   = blockIdx.x * 64 + wv * 16;
    const int b    = r0 >> 13;
    const int rloc = (r0 & 8191) + l15;
    const float* xb = x + (size_t)b * 524288;
    const int id = embed_id[0];

    // x fragments (rows on l15), hi/lo split
    u32x4 xhi[2], xlo[2];
    #pragma unroll
    for (int kc = 0; kc < 2; ++kc) {
        float xv[8];
        #pragma unroll
        for (int j = 0; j < 8; ++j)
            xv[j] = xb[(kc * 32 + quad * 8 + j) * 8192 + rloc];
        pack_hilo(xv, xhi[kc], xlo[kc]);
    }

    // per-lane strength (channel = nt*16+l15) for Q/K; per-reg for V
    float svq_l[4], sv_l[4];
    #pragma unroll
    for (int nt = 0; nt < 4; ++nt) {
        svq_l[nt] = svq_s[nt * 16 + l15];
        sv_l[nt]  = sv_s[nt * 16 + l15];
    }
    f32x4 svA[4];
    #pragma unroll
    for (int mt = 0; mt < 4; ++mt)
        svA[mt] = *(const f32x4*)(&sv_s[mt * 16 + quad * 4]);

    // Q/K store geometry (row = r0 + quad*4 + rr, lane = channel)
    int idxq[4];
    #pragma unroll
    for (int rr = 0; rr < 4; ++rr) {
        const int rl = quad * 4 + rr;
        const int w_ = rl & 7;
        const int s_loc = ((r0 & 8191) >> 3) + (rl >> 3);
        idxq[rr] = (b * 4 + (w_ >> 1)) * 131072 + s_loc * 128 + (w_ & 1) * 64 + l15;
    }
    // V store geometry (lane = row)
    const int row_g = r0 + l15;
    const int s_idx = (row_g >> 3) & 1023;
    const int w_idx = row_g & 7;
    const int bh    = b * 4 + (w_idx >> 1);
    const int dbase = (w_idx & 1) * 64;
    unsigned short* vtb = yvt2 + (size_t)bh * 131072 + (s_idx >> 6) * 8192
                        + (size_t)dbase * 64 + (s_idx & 63);

    for (int mat = 0; mat < 3; ++mat) {
        const float* em = (mat == 0 ? qw : mat == 1 ? kw : vw) + id * 4096;
        const float msc = (mat == 0) ? SCALE : 1.0f;
        // inline emb pack (fragment indexing identical for A- and B-operand)
        u32x4 ehi[4][2], elo[4][2];
        #pragma unroll
        for (int nt = 0; nt < 4; ++nt)
            #pragma unroll
            for (int kc = 0; kc < 2; ++kc) {
                const float* src = em + (nt * 16 + l15) * 64 + kc * 32 + quad * 8;
                f32x4 e0 = *(const f32x4*)src;
                f32x4 e1 = *(const f32x4*)(src + 4);
                float ev[8] = {e0[0] * msc, e0[1] * msc, e0[2] * msc, e0[3] * msc,
                               e1[0] * msc, e1[1] * msc, e1[2] * msc, e1[3] * msc};
                pack_hilo(ev, ehi[nt][kc], elo[nt][kc]);
            }

        f32x4 acc[4] = {};
        if (mat < 2) {
            // swapped operands: A = x, B = emb  -> lane = channel
            #pragma unroll
            for (int kc = 0; kc < 2; ++kc)
                #pragma unroll
                for (int nt = 0; nt < 4; ++nt) {
                    acc[nt] = __builtin_amdgcn_mfma_f32_16x16x32_bf16(
                        __builtin_bit_cast(short8, xhi[kc]),
                        __builtin_bit_cast(short8, ehi[nt][kc]), acc[nt], 0, 0, 0);
                    acc[nt] = __builtin_amdgcn_mfma_f32_16x16x32_bf16(
                        __builtin_bit_cast(short8, xlo[kc]),
                        __builtin_bit_cast(short8, ehi[nt][kc]), acc[nt], 0, 0, 0);
                    acc[nt] = __builtin_amdgcn_mfma_f32_16x16x32_bf16(
                        __builtin_bit_cast(short8, xhi[kc]),
                        __builtin_bit_cast(short8, elo[nt][kc]), acc[nt], 0, 0, 0);
                }
            unsigned short* y = (mat == 0 ? yqh : ykh);
            const float* svp = (mat == 0 ? svq_l : sv_l);
            #pragma unroll
            for (int nt = 0; nt < 4; ++nt)
                #pragma unroll
                for (int rr = 0; rr < 4; ++rr)
                    y[(size_t)idxq[rr] + nt * 16] = f2bf(acc[nt][rr] + svp[nt]);
        } else {
            // V: A = emb, B = x -> lane = row
            #pragma unroll
            for (int kc = 0; kc < 2; ++kc)
                #pragma unroll
                for (int mt = 0; mt < 4; ++mt) {
                    acc[mt] = __builtin_amdgcn_mfma_f32_16x16x32_bf16(
                        __builtin_bit_cast(short8, ehi[mt][kc]),
                        __builtin_bit_cast(short8, xhi[kc]), acc[mt], 0, 0, 0);
                    acc[mt] = __builtin_amdgcn_mfma_f32_16x16x32_bf16(
                        __builtin_bit_cast(short8, ehi[mt][kc]),
                        __builtin_bit_cast(short8, xlo[kc]), acc[mt], 0, 0, 0);
                    acc[mt] = __builtin_amdgcn_mfma_f32_16x16x32_bf16(
                        __builtin_bit_cast(short8, elo[mt][kc]),
                        __builtin_bit_cast(short8, xhi[kc]), acc[mt], 0, 0, 0);
                }
            #pragma unroll
            for (int mt = 0; mt < 4; ++mt)
                #pragma unroll
                for (int rr = 0; rr < 4; ++rr) {
                    const int c = mt * 16 + quad * 4 + rr;
                    vtb[(size_t)c * 64] = f2bf(acc[mt][rr] + svA[mt][rr]);
                }
        }
    }
}

// ---------------------------------------------------------------------------
// K2 k_attn (fused oproj): LDS-staged flash attention; epilogue projects the
// wave's (16q x 64d) quadrant through out_w and writes FINAL out rows.
// Head h feeds exactly out-rows w = 2h+dh; each out row's 64 channels come
// from one wave's d-half.  vbar path: vproj = gf*(vbar@ow^T)+ob in fp32.
// ---------------------------------------------------------------------------
__global__ __launch_bounds__(256, 2) void k_attn(
    const unsigned short* __restrict__ yqh, const unsigned short* __restrict__ ykh,
    const unsigned short* __restrict__ yvt2,
    const float* __restrict__ xbar, const float* __restrict__ vw,
    const int* __restrict__ embed_id, const float* __restrict__ sv_g,
    const float* __restrict__ gate,
    const float* __restrict__ ow, const float* __restrict__ ob,
    float* __restrict__ out)
{
    __shared__ __align__(16) unsigned short kx[2][64 * 136];   // [t][128+8]
    __shared__ __align__(16) unsigned short vx[2][128 * 72];   // [d][64+8]
    __shared__ float vbar_s[128];
    __shared__ float vproj_s[128];

    const int tid  = threadIdx.x;
    const int w    = tid >> 6;
    const int lane = tid & 63;
    const int quad = lane >> 4;
    const int l15  = lane & 15;
    const int bh = blockIdx.x & 15, qt = blockIdx.x >> 4;
    const int b = bh >> 2, h = bh & 3;
    const int s0 = qt * 32;
    const int qh = w >> 1;        // q-half (16 rows)
    const int dh = w & 1;         // d-half (64 cols)

    const unsigned short* ykb = ykh + (size_t)bh * 131072;
    const unsigned short* yvb = yvt2 + (size_t)bh * 131072;
    const float gf = 1.f / (1.f + __expf(-gate[h]));

    // ---- vbar prologue (pos branch, rank-1 reconstruction) ----
    if (tid < 128) {
        const int c = tid & 63, wloc = tid >> 6;
        const float* ver = vw + embed_id[0] * 4096 + c * 64;
        const float* xbr = xbar + (b * 8 + h * 2 + wloc) * 64;
        float a = sv_g[c];
        #pragma unroll
        for (int j4 = 0; j4 < 16; ++j4) {
            f32x4 e4 = *(const f32x4*)(ver + j4 * 4);
            f32x4 x4 = *(const f32x4*)(xbr + j4 * 4);
            a += e4[0] * x4[0] + e4[1] * x4[1] + e4[2] * x4[2] + e4[3] * x4[3];
        }
        vbar_s[wloc * 64 + c] = a;
    }

    // ---- Q fragments: B[n=q(l15)][k=d(quad*8+j)] ----
    u32x4 qf[4];
    #pragma unroll
    for (int kc = 0; kc < 4; ++kc)
        qf[kc] = *(const u32x4*)(yqh + (size_t)bh * 131072
                 + (s0 + qh * 16 + l15) * 128 + kc * 32 + quad * 8);

    // ---- stage tile 0 ----
    #pragma unroll
    for (int r = 0; r < 4; ++r) {
        const int off = r * 2048 + tid * 8;
        *(u32x4*)&kx[0][(off >> 7) * 136 + (off & 127)] =
            *(const u32x4*)(ykb + off);
        *(u32x4*)&vx[0][(off >> 6) * 72 + (off & 63)] =
            *(const u32x4*)(yvb + off);
    }
    __syncthreads();

    // ---- vproj = gf*(vbar_dh @ ow^T) + ob  (fp32, once per block) ----
    if (tid < 128) {
        const int cp = tid & 63, w2 = tid >> 6;
        const float* owr = ow + cp * 64;
        const float* vb = vbar_s + w2 * 64;
        float a = 0.f;
        #pragma unroll
        for (int j4 = 0; j4 < 16; ++j4) {
            f32x4 o4 = *(const f32x4*)(owr + j4 * 4);
            f32x4 v4 = *(const f32x4*)(vb + j4 * 4);
            a += o4[0] * v4[0] + o4[1] * v4[1] + o4[2] * v4[2] + o4[3] * v4[3];
        }
        vproj_s[tid] = gf * a + ob[cp];
    }

    f32x4 o[4] = {};
    float lsum = 0.f;
    const int srcA = ((quad & 1) << 5) + l15;

    for (int it = 0; it < 16; ++it) {
        const int cur = it & 1;
        u32x4 kst[4], vst[4];
        const bool pre = (it < 15);
        if (pre) {
            const unsigned short* ksrc = ykb + (it + 1) * 8192;
            const unsigned short* vsrc = yvb + (it + 1) * 8192;
            #pragma unroll
            for (int r = 0; r < 4; ++r)
                kst[r] = *(const u32x4*)(ksrc + r * 2048 + tid * 8);
            #pragma unroll
            for (int r = 0; r < 4; ++r)
                vst[r] = *(const u32x4*)(vsrc + r * 2048 + tid * 8);
        }

        const unsigned short* kxc = kx[cur];
        const unsigned short* vxc = vx[cur];

        #pragma unroll
        for (int th = 0; th < 2; ++th) {
            f32x4 sa0 = {}, sa1 = {};
            #pragma unroll
            for (int kc = 0; kc < 4; ++kc) {
                u32x4 a0 = *(const u32x4*)&kxc[(th * 32 + l15) * 136 + kc * 32 + quad * 8];
                sa0 = __builtin_amdgcn_mfma_f32_16x16x32_bf16(
                    __builtin_bit_cast(short8, a0),
                    __builtin_bit_cast(short8, qf[kc]), sa0, 0, 0, 0);
            }
            #pragma unroll
            for (int kc = 0; kc < 4; ++kc) {
                u32x4 a1 = *(const u32x4*)&kxc[(th * 32 + 16 + l15) * 136 + kc * 32 + quad * 8];
                sa1 = __builtin_amdgcn_mfma_f32_16x16x32_bf16(
                    __builtin_bit_cast(short8, a1),
                    __builtin_bit_cast(short8, qf[kc]), sa1, 0, 0, 0);
            }

            float p0[4], p1[4];
            #pragma unroll
            for (int r = 0; r < 4; ++r) {
                p0[r] = __expf(sa0[r] - SOFT_C);
                p1[r] = __expf(sa1[r] - SOFT_C);
                lsum += p0[r] + p1[r];
            }

            unsigned int pk00 = (unsigned int)f2bf(p0[0]) | ((unsigned int)f2bf(p0[1]) << 16);
            unsigned int pk01 = (unsigned int)f2bf(p0[2]) | ((unsigned int)f2bf(p0[3]) << 16);
            unsigned int pk10 = (unsigned int)f2bf(p1[0]) | ((unsigned int)f2bf(p1[1]) << 16);
            unsigned int pk11 = (unsigned int)f2bf(p1[2]) | ((unsigned int)f2bf(p1[3]) << 16);
            unsigned int sel0 = (quad < 2) ? pk00 : pk10;
            unsigned int sel1 = (quad < 2) ? pk01 : pk11;
            u32x4 pf;
            pf[0] = (unsigned int)__shfl((int)sel0, srcA);
            pf[1] = (unsigned int)__shfl((int)sel1, srcA);
            pf[2] = (unsigned int)__shfl((int)sel0, srcA + 16);
            pf[3] = (unsigned int)__shfl((int)sel1, srcA + 16);

            #pragma unroll
            for (int dt = 0; dt < 4; ++dt) {
                u32x4 vf = *(const u32x4*)&vxc[(dh * 64 + dt * 16 + l15) * 72
                                               + th * 32 + quad * 8];
                o[dt] = __builtin_amdgcn_mfma_f32_16x16x32_bf16(
                    __builtin_bit_cast(short8, vf),
                    __builtin_bit_cast(short8, pf), o[dt], 0, 0, 0);
            }
        }

        if (pre) {
            #pragma unroll
            for (int r = 0; r < 4; ++r) {
                const int off = r * 2048 + tid * 8;
                *(u32x4*)&kx[cur ^ 1][(off >> 7) * 136 + (off & 127)] = kst[r];
            }
            #pragma unroll
            for (int r = 0; r < 4; ++r) {
                const int off = r * 2048 + tid * 8;
                *(u32x4*)&vx[cur ^ 1][(off >> 6) * 72 + (off & 63)] = vst[r];
            }
        }
        __syncthreads();
    }

    // ---- fused output projection epilogue ----
    lsum += __shfl_xor(lsum, 16);
    lsum += __shfl_xor(lsum, 32);
    const float cf = (1.f - gf) / lsum;

    // Y = cf*o -> wave-private LDS (reuse kx; all waves past final barrier),
    // hi/lo split for split-bf16 projection.
    unsigned short* yst = (unsigned short*)kx + w * 4352;   // hi: [q][68], lo at +1088
    #pragma unroll
    for (int dt = 0; dt < 4; ++dt) {
        f32x4 yv = o[dt];
        unsigned int hh[4];
        unsigned short ll[4];
        #pragma unroll
        for (int r = 0; r < 4; ++r) {
            float y = cf * yv[r];
            hh[r] = f2bf(y);
            ll[r] = f2bf(y - bf2f(hh[r]));
        }
        const int dloc = dt * 16 + quad * 4;
        u32x2 ph_, pl_;
        ph_[0] = hh[0] | (hh[1] << 16);
        ph_[1] = hh[2] | (hh[3] << 16);
        pl_[0] = (unsigned int)ll[0] | ((unsigned int)ll[1] << 16);
        pl_[1] = (unsigned int)ll[2] | ((unsigned int)ll[3] << 16);
        *(u32x2*)&yst[l15 * 68 + dloc] = ph_;
        *(u32x2*)&yst[1088 + l15 * 68 + dloc] = pl_;
    }
    // B-fragments of Y (n = q on l15, k = d)
    u32x4 ybh[2], ybl[2];
    #pragma unroll
    for (int kc = 0; kc < 2; ++kc) {
        ybh[kc] = *(const u32x4*)&yst[l15 * 68 + kc * 32 + quad * 8];
        ybl[kc] = *(const u32x4*)&yst[1088 + l15 * 68 + kc * 32 + quad * 8];
    }
    // A-fragments of out_w (inline fp32 -> hi/lo) + MFMA
    f32x4 accp[4] = {};
    #pragma unroll
    for (int kc = 0; kc < 2; ++kc)
        #pragma unroll
        for (int mt = 0; mt < 4; ++mt) {
            const float* src = ow + (mt * 16 + l15) * 64 + kc * 32 + quad * 8;
            f32x4 e0 = *(const f32x4*)src;
            f32x4 e1 = *(const f32x4*)(src + 4);
            float ev[8] = {e0[0], e0[1], e0[2], e0[3], e1[0], e1[1], e1[2], e1[3]};
            u32x4 ohi, olo;
            pack_hilo(ev, ohi, olo);
            accp[mt] = __builtin_amdgcn_mfma_f32_16x16x32_bf16(
                __builtin_bit_cast(short8, ohi),
                __builtin_bit_cast(short8, ybh[kc]), accp[mt], 0, 0, 0);
            accp[mt] = __builtin_amdgcn_mfma_f32_16x16x32_bf16(
                __builtin_bit_cast(short8, ohi),
                __builtin_bit_cast(short8, ybl[kc]), accp[mt], 0, 0, 0);
            accp[mt] = __builtin_amdgcn_mfma_f32_16x16x32_bf16(
                __builtin_bit_cast(short8, olo),
                __builtin_bit_cast(short8, ybh[kc]), accp[mt], 0, 0, 0);
        }
    // store final out rows: row (b, s=s0+qh*16+l15, w=2h+dh)
    const int sQ = s0 + qh * 16 + l15;
    float* op = out + ((size_t)((b * S_ + sQ) * 8 + 2 * h + dh)) * 64;
    #pragma unroll
    for (int mt = 0; mt < 4; ++mt) {
        f32x4 vp = *(const f32x4*)&vproj_s[dh * 64 + mt * 16 + quad * 4];
        f32x4 rv = accp[mt] + vp;
        *(f32x4*)(op + mt * 16 + quad * 4) = rv;
    }
}

extern "C" void kernel_launch(void* const* d_in, const int* in_sizes, int n_in,
                              void* d_out, int out_size, void* d_ws, size_t ws_size,
                              hipStream_t stream) {
    (void)in_sizes; (void)n_in; (void)out_size; (void)ws_size;
    const float* x        = (const float*)d_in[0];
    const float* pos      = (const float*)d_in[1];
    const float* strength = (const float*)d_in[2];
    const int*   embed_id = (const int*)d_in[3];
    const float* qw       = (const float*)d_in[4];
    const float* kw       = (const float*)d_in[5];
    const float* vw       = (const float*)d_in[6];
    const float* pw1      = (const float*)d_in[7];
    const float* pb1      = (const float*)d_in[8];
    const float* pw2      = (const float*)d_in[9];
    const float* pb2      = (const float*)d_in[10];
    const float* head_w   = (const float*)d_in[11];
    const float* gate     = (const float*)d_in[13];
    const float* out_w    = (const float*)d_in[14];
    const float* out_b    = (const float*)d_in[15];
    const float* str_w    = (const float*)d_in[16];
    const float* str_b    = (const float*)d_in[17];
    float* out = (float*)d_out;

    unsigned short* yqh  = (unsigned short*)d_ws;          // 4 MiB
    unsigned short* ykh  = yqh + 2097152;                  // 4 MiB
    unsigned short* yvt2 = ykh + 2097152;                  // 4 MiB
    float* xbar = (float*)(yvt2 + 2097152);                // 2048 floats
    float* sv_g = xbar + 2048;                             // 64 floats

    k_qkv<<<768, 256, 0, stream>>>(x, strength, embed_id, qw, kw, vw,
                                   str_w, str_b, pos, pw1, pb1, pw2, pb2,
                                   head_w, yqh, ykh, yvt2, xbar, sv_g);
    k_attn<<<512, 256, 0, stream>>>(yqh, ykh, yvt2, xbar, vw, embed_id, sv_g,
                                    gate, out_w, out_b, out);
}